// Round 5
// baseline (2741.654 us; speedup 1.0000x reference)
//
#include <hip/hip_runtime.h>
#include <hip/hip_bf16.h>
#include <stdint.h>

// ParaGraph: 2 node types (net/cell, N=100000), 3 relations (E=600000 each), D=128.
// I/O FP32. bf16 MFMA GEMMs; bucket-CSR + LDS-accumulating softmax aggregation.
#define NN 100000
#define NE 600000
#define SP 136       // GEMM LDS row stride (ushorts): 128 + 8 pad
#define NB 782       // ceil(NN/128) dst buckets of 128 nodes

typedef unsigned short u16;
typedef unsigned int u32;
typedef __attribute__((ext_vector_type(8))) short short8;
typedef __attribute__((ext_vector_type(8))) __bf16 bf16x8;
typedef __attribute__((ext_vector_type(4))) float floatx4;

__device__ __forceinline__ float b2f(u16 u) {
  union { float f; u32 i; } c; c.i = ((u32)u) << 16; return c.f;
}
__device__ __forceinline__ u16 f2b(float f) {
  union { float f; u32 i; } c; c.f = f;
  u32 r = c.i + 0x7FFFu + ((c.i >> 16) & 1u);  // RNE
  return (u16)(r >> 16);
}

// ---------- feature projection: feat = x @ Wp.T, [N,16]x[16,128] -> bf16 [N,128]
__global__ __launch_bounds__(256) void proj_k(const float* __restrict__ x_net, const float* __restrict__ x_cell,
                                              const float* __restrict__ Wp_net, const float* __restrict__ Wp_cell,
                                              u16* __restrict__ feat_net, u16* __restrict__ feat_cell) {
  const float* x  = blockIdx.y ? x_cell : x_net;
  const float* Wp = blockIdx.y ? Wp_cell : Wp_net;
  u16* feat       = blockIdx.y ? feat_cell : feat_net;
  __shared__ float Ws[128 * 17];
  __shared__ float xs[16][17];
  int tid = threadIdx.x;
#pragma unroll
  for (int it = 0; it < 8; ++it) {
    int idx = it * 256 + tid;
    int j = idx >> 4, k = idx & 15;
    Ws[j * 17 + k] = Wp[idx];
  }
  int n0 = blockIdx.x * 16;
  { int nn = tid >> 4, k = tid & 15;
    xs[nn][k] = x[(size_t)(n0 + nn) * 16 + k]; }
  __syncthreads();
  int j = tid & 127, g = tid >> 7;
  float acc[8];
#pragma unroll
  for (int r = 0; r < 8; ++r) acc[r] = 0.f;
#pragma unroll
  for (int k = 0; k < 16; ++k) {
    float w = Ws[j * 17 + k];
#pragma unroll
    for (int r = 0; r < 8; ++r) acc[r] += xs[g * 8 + r][k] * w;
  }
#pragma unroll
  for (int r = 0; r < 8; ++r)
    feat[(size_t)(n0 + g * 8 + r) * 128 + j] = f2b(acc[r]);
}

// ---------- vectors: a<6: vecs[a][k] = sum_j Wg[j,k]*(al|ar)[j];  a==6: c[j] = sum_k bias[k]*W2[j,k]
__global__ __launch_bounds__(128) void vec_k(const float* Wg0, const float* al0, const float* ar0,
                                             const float* Wg1, const float* al1, const float* ar1,
                                             const float* Wg2, const float* al2, const float* ar2,
                                             const float* Wl, const float* bias,
                                             float* __restrict__ vecs) {
  int a = blockIdx.x;
  int j = threadIdx.x;
  float s = 0.f;
  if (a < 6) {
    const float* W = (a < 2) ? Wg0 : (a < 4) ? Wg1 : Wg2;
    const float* v = (a == 0) ? al0 : (a == 1) ? ar0 : (a == 2) ? al1 : (a == 3) ? ar1 : (a == 4) ? al2 : ar2;
    for (int i = 0; i < 128; ++i) s += W[i * 128 + j] * v[i];
  } else {
    for (int i = 0; i < 128; ++i) s += Wl[(size_t)j * 256 + 128 + i] * bias[i];
  }
  vecs[a * 128 + j] = s;
}

// ---------- per-node logits, single pass per ntype:
// y=0 (net): a=1 er0, a=2 el1, a=4 el2, a=5 er2;  y=1 (cell): a=0 el0, a=3 er1
__global__ __launch_bounds__(256) void logits_k(const u16* __restrict__ feat_net, const u16* __restrict__ feat_cell,
                                                const float* __restrict__ vecs, float* __restrict__ outs) {
  __shared__ float vs[6 * 128];
  int tid = threadIdx.x;
#pragma unroll
  for (int it = 0; it < 3; ++it) vs[it * 256 + tid] = vecs[it * 256 + tid];
  __syncthreads();
  int y = blockIdx.y;
  const u16* f = y ? feat_cell : feat_net;
  int n = blockIdx.x * 256 + tid;
  if (n >= NN) return;
  const u16* row = f + (size_t)n * 128;
  if (y == 0) {
    float s1 = 0.f, s2 = 0.f, s4 = 0.f, s5 = 0.f;
#pragma unroll
    for (int k = 0; k < 128; k += 8) {
      short8 u = *(const short8*)(row + k);
#pragma unroll
      for (int t = 0; t < 8; ++t) {
        float fv = b2f((u16)u[t]);
        s1 += fv * vs[1 * 128 + k + t]; s2 += fv * vs[2 * 128 + k + t];
        s4 += fv * vs[4 * 128 + k + t]; s5 += fv * vs[5 * 128 + k + t];
      }
    }
    outs[(size_t)1 * NN + n] = s1; outs[(size_t)2 * NN + n] = s2;
    outs[(size_t)4 * NN + n] = s4; outs[(size_t)5 * NN + n] = s5;
  } else {
    float s0 = 0.f, s3 = 0.f;
#pragma unroll
    for (int k = 0; k < 128; k += 8) {
      short8 u = *(const short8*)(row + k);
#pragma unroll
      for (int t = 0; t < 8; ++t) {
        float fv = b2f((u16)u[t]);
        s0 += fv * vs[0 * 128 + k + t]; s3 += fv * vs[3 * 128 + k + t];
      }
    }
    outs[(size_t)0 * NN + n] = s0; outs[(size_t)3 * NN + n] = s3;
  }
}

// ---------- bucket histogram (buckets of 128 dst nodes)
__global__ __launch_bounds__(256) void bhist_k(const int* __restrict__ dst0, const int* __restrict__ dst1,
                                               const int* __restrict__ dst2, int* __restrict__ bcnt) {
  int r = blockIdx.y;
  const int* dst = (r == 0) ? dst0 : (r == 1) ? dst1 : dst2;
  int e = blockIdx.x * 256 + threadIdx.x;
  if (e >= NE) return;
  atomicAdd(&bcnt[r * NB + (dst[e] >> 7)], 1);
}

// ---------- bucket exclusive scan (one 1024-block per relation)
__global__ __launch_bounds__(1024) void bscan_k(const int* __restrict__ bcnt, int* __restrict__ bptr,
                                                int* __restrict__ bcur) {
  int r = blockIdx.x, t = threadIdx.x;
  __shared__ int ss[1024];
  int v = (t < NB) ? bcnt[r * NB + t] : 0;
  ss[t] = v; __syncthreads();
  for (int off = 1; off < 1024; off <<= 1) {
    int u = (t >= off) ? ss[t - off] : 0;
    __syncthreads();
    ss[t] += u;
    __syncthreads();
  }
  if (t < NB) { int ex = ss[t] - v; bptr[(size_t)r * (NB + 1) + t] = ex; bcur[r * NB + t] = ex; }
  if (t == 1023) bptr[(size_t)r * (NB + 1) + NB] = ss[1023];
}

// ---------- bucket scatter: rec = (local_dst<<17) | src  (4B per edge)
__global__ __launch_bounds__(256) void bscatter_k(const int* __restrict__ src0, const int* __restrict__ dst0,
                                                  const int* __restrict__ src1, const int* __restrict__ dst1,
                                                  const int* __restrict__ src2, const int* __restrict__ dst2,
                                                  int* __restrict__ bcur, u32* __restrict__ recs) {
  int r = blockIdx.y;
  const int* src = (r == 0) ? src0 : (r == 1) ? src1 : src2;
  const int* dst = (r == 0) ? dst0 : (r == 1) ? dst1 : dst2;
  int e = blockIdx.x * 256 + threadIdx.x;
  if (e >= NE) return;
  int sN = src[e], dN = dst[e];
  int pos = atomicAdd(&bcur[r * NB + (dN >> 7)], 1);
  recs[(size_t)r * NE + pos] = ((u32)(dN & 127) << 17) | (u32)sN;
}

// ---------- aggregation: one block per bucket; 128x128 fp32 out-tile in LDS
// out[n] (+)= (sum_e ex_e * h[src_e]) / (sum_e ex_e);  ex = exp(leaky(el[src]+er[n]))
template<int RMW>
__global__ __launch_bounds__(256) void agg_lds_k(const u16* __restrict__ h, const u32* __restrict__ recs,
                                                 const int* __restrict__ bptr,
                                                 const float* __restrict__ el, const float* __restrict__ er,
                                                 float* __restrict__ out) {
  __shared__ float acc_s[128 * 128];   // 64 KB
  __shared__ float den_s[128];
  __shared__ float er_s[128];
  int b = blockIdx.x, tid = threadIdx.x;
  for (int i = tid; i < 128 * 128; i += 256) acc_s[i] = 0.f;
  if (tid < 128) {
    den_s[tid] = 0.f;
    int node = b * 128 + tid;
    er_s[tid] = (node < NN) ? er[node] : 0.f;
  }
  __syncthreads();
  int base = bptr[b], end = bptr[b + 1];
  int wv = tid >> 6, lane = tid & 63;
  for (int i = base + wv; i < end; i += 4) {
    u32 rec = recs[i];
    int src = (int)(rec & 0x1FFFFu);
    int ld  = (int)(rec >> 17);
    float l = el[src] + er_s[ld];
    l = (l >= 0.f) ? l : 0.2f * l;
    float x = __expf(l);
    if (lane == 0) atomicAdd(&den_s[ld], x);
    u32 hv = *(const u32*)(h + (size_t)src * 128 + 2 * lane);
    atomicAdd(&acc_s[ld * 128 + 2 * lane],     x * b2f((u16)(hv & 0xffff)));
    atomicAdd(&acc_s[ld * 128 + 2 * lane + 1], x * b2f((u16)(hv >> 16)));
  }
  __syncthreads();
  for (int idx = tid; idx < 128 * 64; idx += 256) {
    int row = idx >> 6, cp = idx & 63;
    int node = b * 128 + row;
    if (node >= NN) continue;
    float d = den_s[row];
    float2 prev = RMW ? ((float2*)out)[(size_t)node * 64 + cp] : make_float2(0.f, 0.f);
    if (d > 0.f) {
      float inv = 1.f / d;
      prev.x += acc_s[row * 128 + 2 * cp] * inv;
      prev.y += acc_s[row * 128 + 2 * cp + 1] * inv;
    }
    ((float2*)out)[(size_t)node * 64 + cp] = prev;
  }
}

// ---------- bf16 GEMM (up to 3 jobs): C[n][j] = sum_k A[n][k] * W[j*ldw+woff+k], bf16 out
struct BJob { const u16* A; const float* W; int ldw; int woff; u16* C; };
struct BJobs3 { BJob j[3]; };
__global__ __launch_bounds__(256) void gemm_bf_k(BJobs3 jobs) {
  BJob jb = jobs.j[blockIdx.y];
  __shared__ u16 Alds[64 * SP];
  __shared__ u16 Wlds[128 * SP];
  const int tid = threadIdx.x;
  const int row0 = blockIdx.x * 64;
#pragma unroll
  for (int it = 0; it < 16; ++it) {
    int idx = it * 256 + tid;
    int r = idx >> 5, c = (idx & 31) << 2;
    float4 v = *(const float4*)(jb.W + (size_t)r * jb.ldw + jb.woff + c);
    ushort4 p; p.x = f2b(v.x); p.y = f2b(v.y); p.z = f2b(v.z); p.w = f2b(v.w);
    *(ushort4*)(&Wlds[r * SP + c]) = p;
  }
#pragma unroll
  for (int it = 0; it < 4; ++it) {
    int idx = it * 256 + tid;
    int r = idx >> 4, c = (idx & 15) << 3;
    int gr = row0 + r;
    short8 v = short8{0, 0, 0, 0, 0, 0, 0, 0};
    if (gr < NN) v = *(const short8*)(jb.A + (size_t)gr * 128 + c);
    *(short8*)(&Alds[r * SP + c]) = v;
  }
  __syncthreads();
  const int lane = tid & 63, wv = tid >> 6;
  const int m16 = lane & 15, quad = lane >> 4;
  floatx4 acc[8];
#pragma unroll
  for (int c = 0; c < 8; ++c) acc[c] = floatx4{0.f, 0.f, 0.f, 0.f};
  const u16* arow = &Alds[(wv * 16 + m16) * SP + quad * 8];
  const u16* brow = &Wlds[m16 * SP + quad * 8];
#pragma unroll
  for (int kk = 0; kk < 4; ++kk) {
    bf16x8 a = *(const bf16x8*)(arow + kk * 32);
#pragma unroll
    for (int c = 0; c < 8; ++c) {
      bf16x8 bfr = *(const bf16x8*)(brow + c * 16 * SP + kk * 32);
      acc[c] = __builtin_amdgcn_mfma_f32_16x16x32_bf16(a, bfr, acc[c], 0, 0, 0);
    }
  }
#pragma unroll
  for (int c = 0; c < 8; ++c) {
    int col = c * 16 + m16;
#pragma unroll
    for (int r = 0; r < 4; ++r) {
      int grow = row0 + wv * 16 + quad * 4 + r;
      if (grow < NN) jb.C[(size_t)grow * 128 + col] = f2b(acc[c][r]);
    }
  }
}

// ---------- fused concat-linear-relu (up to 2 jobs): C = relu(P + (A+bias) @ W2.T), fp32 out
struct FJob { const float* A; const u16* P; float* C; };
struct FJobs2 { FJob j[2]; const float* W; const float* bias; };
__global__ __launch_bounds__(256) void fused_k(FJobs2 jobs) {
  FJob jb = jobs.j[blockIdx.y];
  __shared__ u16 Alds[64 * SP];
  __shared__ u16 Wlds[128 * SP];
  const int tid = threadIdx.x;
  const int row0 = blockIdx.x * 64;
#pragma unroll
  for (int it = 0; it < 16; ++it) {
    int idx = it * 256 + tid;
    int r = idx >> 5, c = (idx & 31) << 2;
    float4 v = *(const float4*)(jobs.W + (size_t)r * 256 + 128 + c);
    ushort4 p; p.x = f2b(v.x); p.y = f2b(v.y); p.z = f2b(v.z); p.w = f2b(v.w);
    *(ushort4*)(&Wlds[r * SP + c]) = p;
  }
#pragma unroll
  for (int it = 0; it < 8; ++it) {
    int idx = it * 256 + tid;
    int r = idx >> 5, col = (idx & 31) << 2;
    int gr = row0 + r;
    float4 v = make_float4(0.f, 0.f, 0.f, 0.f);
    if (gr < NN) v = *(const float4*)(jb.A + (size_t)gr * 128 + col);
    v.x += jobs.bias[col]; v.y += jobs.bias[col + 1];
    v.z += jobs.bias[col + 2]; v.w += jobs.bias[col + 3];
    ushort4 p; p.x = f2b(v.x); p.y = f2b(v.y); p.z = f2b(v.z); p.w = f2b(v.w);
    *(ushort4*)(&Alds[r * SP + col]) = p;
  }
  __syncthreads();
  const int lane = tid & 63, wv = tid >> 6;
  const int m16 = lane & 15, quad = lane >> 4;
  floatx4 acc[8];
#pragma unroll
  for (int c = 0; c < 8; ++c) acc[c] = floatx4{0.f, 0.f, 0.f, 0.f};
  const u16* arow = &Alds[(wv * 16 + m16) * SP + quad * 8];
  const u16* brow = &Wlds[m16 * SP + quad * 8];
#pragma unroll
  for (int kk = 0; kk < 4; ++kk) {
    bf16x8 a = *(const bf16x8*)(arow + kk * 32);
#pragma unroll
    for (int c = 0; c < 8; ++c) {
      bf16x8 bfr = *(const bf16x8*)(brow + c * 16 * SP + kk * 32);
      acc[c] = __builtin_amdgcn_mfma_f32_16x16x32_bf16(a, bfr, acc[c], 0, 0, 0);
    }
  }
#pragma unroll
  for (int c = 0; c < 8; ++c) {
    int col = c * 16 + m16;
#pragma unroll
    for (int r = 0; r < 4; ++r) {
      int grow = row0 + wv * 16 + quad * 4 + r;
      if (grow < NN) {
        float v = acc[c][r] + b2f(jb.P[(size_t)grow * 128 + col]);
        jb.C[(size_t)grow * 128 + col] = fmaxf(v, 0.f);
      }
    }
  }
}

// ---------- r0 cell shortcut: buf_cell = relu(P_cell + c)   (input buf was all zeros)
__global__ __launch_bounds__(256) void elem_k(const u16* __restrict__ P, const float* __restrict__ vecs,
                                              float* __restrict__ out) {
  __shared__ float cs[128];
  if (threadIdx.x < 128) cs[threadIdx.x] = vecs[6 * 128 + threadIdx.x];
  __syncthreads();
  size_t idx = ((size_t)blockIdx.x * 256 + threadIdx.x) * 8;
  if (idx >= (size_t)NN * 128) return;
  int col = (int)(idx & 127);
  short8 u = *(const short8*)(P + idx);
  float4 o0, o1;
  o0.x = fmaxf(b2f((u16)u[0]) + cs[col + 0], 0.f);
  o0.y = fmaxf(b2f((u16)u[1]) + cs[col + 1], 0.f);
  o0.z = fmaxf(b2f((u16)u[2]) + cs[col + 2], 0.f);
  o0.w = fmaxf(b2f((u16)u[3]) + cs[col + 3], 0.f);
  o1.x = fmaxf(b2f((u16)u[4]) + cs[col + 4], 0.f);
  o1.y = fmaxf(b2f((u16)u[5]) + cs[col + 5], 0.f);
  o1.z = fmaxf(b2f((u16)u[6]) + cs[col + 6], 0.f);
  o1.w = fmaxf(b2f((u16)u[7]) + cs[col + 7], 0.f);
  *(float4*)(out + idx) = o0;
  *(float4*)(out + idx + 4) = o1;
}

extern "C" void kernel_launch(void* const* d_in, const int* in_sizes, int n_in,
                              void* d_out, int out_size, void* d_ws, size_t ws_size,
                              hipStream_t stream) {
  const float* x_net   = (const float*)d_in[0];
  const float* x_cell  = (const float*)d_in[1];
  const float* Wp_net  = (const float*)d_in[2];
  const float* Wp_cell = (const float*)d_in[3];
  const float* Wg[3] = {(const float*)d_in[4], (const float*)d_in[7], (const float*)d_in[10]};
  const float* al[3] = {(const float*)d_in[5], (const float*)d_in[8], (const float*)d_in[11]};
  const float* ar[3] = {(const float*)d_in[6], (const float*)d_in[9], (const float*)d_in[12]};
  const float* Wl    = (const float*)d_in[13];
  const float* bias  = (const float*)d_in[14];
  const int* src[3] = {(const int*)d_in[15], (const int*)d_in[17], (const int*)d_in[19]};
  const int* dst[3] = {(const int*)d_in[16], (const int*)d_in[18], (const int*)d_in[20]};

  char* ws = (char*)d_ws;
  size_t off = 0;
  auto alloc = [&](size_t b) { void* p = ws + off; off = (off + b + 255) & ~(size_t)255; return p; };
  u16*  feat_net  = (u16*)alloc((size_t)NN * 128 * 2);
  u16*  feat_cell = (u16*)alloc((size_t)NN * 128 * 2);
  u16*  hbuf      = (u16*)alloc((size_t)NN * 128 * 2);
  u16*  P_net     = (u16*)alloc((size_t)NN * 128 * 2);
  u16*  P_cell    = (u16*)alloc((size_t)NN * 128 * 2);
  float* buf_net  = (float*)alloc((size_t)NN * 128 * 4);
  float* buf_cell = (float*)alloc((size_t)NN * 128 * 4);
  float* vecs     = (float*)alloc(7 * 128 * 4);
  float* logit    = (float*)alloc((size_t)6 * NN * 4);
  int*   bcnt     = (int*)alloc((size_t)3 * NB * 4);
  int*   bcur     = (int*)alloc((size_t)3 * NB * 4);
  int*   bptr     = (int*)alloc((size_t)3 * (NB + 1) * 4);
  u32*   recs     = (u32*)alloc((size_t)3 * NE * 4);
  // ~240 MB total

  hipMemsetAsync(bcnt, 0, (size_t)3 * NB * 4, stream);

  proj_k<<<dim3(NN / 16, 2), 256, 0, stream>>>(x_net, x_cell, Wp_net, Wp_cell, feat_net, feat_cell);
  vec_k<<<7, 128, 0, stream>>>(Wg[0], al[0], ar[0], Wg[1], al[1], ar[1], Wg[2], al[2], ar[2], Wl, bias, vecs);
  logits_k<<<dim3((NN + 255) / 256, 2), 256, 0, stream>>>(feat_net, feat_cell, vecs, logit);

  bhist_k<<<dim3((NE + 255) / 256, 3), 256, 0, stream>>>(dst[0], dst[1], dst[2], bcnt);
  bscan_k<<<3, 1024, 0, stream>>>(bcnt, bptr, bcur);
  bscatter_k<<<dim3((NE + 255) / 256, 3), 256, 0, stream>>>(src[0], dst[0], src[1], dst[1], src[2], dst[2],
                                                            bcur, recs);

  const int gb = (NN + 63) / 64;  // 1563
  // P_net, P_cell, h0 in one dispatch
  {
    BJobs3 jobs;
    jobs.j[0] = {feat_net,  Wl,    256, 0, P_net};
    jobs.j[1] = {feat_cell, Wl,    256, 0, P_cell};
    jobs.j[2] = {feat_cell, Wg[0], 128, 0, hbuf};   // h0 = feat_cell @ Wg0.T
    gemm_bf_k<<<dim3(gb, 3), 256, 0, stream>>>(jobs);
  }

  float* out_f = (float*)d_out;  // [2,N,D] fp32: net then cell

  // ---- r = 0 : cell -> net
  agg_lds_k<0><<<NB, 256, 0, stream>>>(hbuf, recs, bptr, logit, logit + (size_t)NN, buf_net);
  {
    FJobs2 jobs; jobs.W = Wl; jobs.bias = bias;
    jobs.j[0] = {buf_net, P_net, buf_net}; jobs.j[1] = jobs.j[0];
    fused_k<<<dim3(gb, 1), 256, 0, stream>>>(jobs);
  }
  elem_k<<<(NN * 128 / 8 + 255) / 256, 256, 0, stream>>>(P_cell, vecs, buf_cell);

  // ---- r = 1 : net -> cell
  {
    BJobs3 jobs;
    jobs.j[0] = {feat_net, Wg[1], 128, 0, hbuf};
    jobs.j[1] = jobs.j[0]; jobs.j[2] = jobs.j[0];
    gemm_bf_k<<<dim3(gb, 1), 256, 0, stream>>>(jobs);
  }
  agg_lds_k<1><<<NB, 256, 0, stream>>>(hbuf, recs + (size_t)NE, bptr + (NB + 1),
                                       logit + (size_t)2 * NN, logit + (size_t)3 * NN, buf_cell);
  {
    FJobs2 jobs; jobs.W = Wl; jobs.bias = bias;
    jobs.j[0] = {buf_net, P_net, buf_net};
    jobs.j[1] = {buf_cell, P_cell, buf_cell};
    fused_k<<<dim3(gb, 2), 256, 0, stream>>>(jobs);
  }

  // ---- r = 2 : net -> net
  {
    BJobs3 jobs;
    jobs.j[0] = {feat_net, Wg[2], 128, 0, hbuf};
    jobs.j[1] = jobs.j[0]; jobs.j[2] = jobs.j[0];
    gemm_bf_k<<<dim3(gb, 1), 256, 0, stream>>>(jobs);
  }
  agg_lds_k<1><<<NB, 256, 0, stream>>>(hbuf, recs + (size_t)2 * NE, bptr + 2 * (NB + 1),
                                       logit + (size_t)4 * NN, logit + (size_t)5 * NN, buf_net);
  {
    FJobs2 jobs; jobs.W = Wl; jobs.bias = bias;
    jobs.j[0] = {buf_net, P_net, out_f};
    jobs.j[1] = {buf_cell, P_cell, out_f + (size_t)NN * 128};
    fused_k<<<dim3(gb, 2), 256, 0, stream>>>(jobs);
  }
}

// Round 6
// 883.387 us; speedup vs baseline: 3.1036x; 3.1036x over previous
//
#include <hip/hip_runtime.h>
#include <hip/hip_bf16.h>
#include <stdint.h>

// ParaGraph: 2 node types (net/cell, N=100000), 3 relations (E=600000 each), D=128.
// I/O FP32. bf16 MFMA GEMMs; bucket-scatter (16 sub-cursors) + per-bucket LDS counting
// sort -> node-CSR; wave-per-node register-accumulating softmax aggregation.
#define NN 100000
#define NE 600000
#define SP 136        // GEMM LDS row stride (ushorts): 128 + 8 pad
#define NB 782        // ceil(NN/128) dst buckets of 128 nodes
#define NSUB 16       // sub-cursors per bucket (contention fix)
#define NK (NB*NSUB)  // counters per relation = 12512
#define BCAP 1600     // LDS rec capacity per bucket (mean 767, sd ~28)

typedef unsigned short u16;
typedef unsigned int u32;
typedef __attribute__((ext_vector_type(8))) short short8;
typedef __attribute__((ext_vector_type(8))) __bf16 bf16x8;
typedef __attribute__((ext_vector_type(4))) float floatx4;

__device__ __forceinline__ float b2f(u16 u) {
  union { float f; u32 i; } c; c.i = ((u32)u) << 16; return c.f;
}
__device__ __forceinline__ u16 f2b(float f) {
  union { float f; u32 i; } c; c.f = f;
  u32 r = c.i + 0x7FFFu + ((c.i >> 16) & 1u);  // RNE
  return (u16)(r >> 16);
}

// ---------- feature projection: feat = x @ Wp.T, [N,16]x[16,128] -> bf16 [N,128]
__global__ __launch_bounds__(256) void proj_k(const float* __restrict__ x_net, const float* __restrict__ x_cell,
                                              const float* __restrict__ Wp_net, const float* __restrict__ Wp_cell,
                                              u16* __restrict__ feat_net, u16* __restrict__ feat_cell) {
  const float* x  = blockIdx.y ? x_cell : x_net;
  const float* Wp = blockIdx.y ? Wp_cell : Wp_net;
  u16* feat       = blockIdx.y ? feat_cell : feat_net;
  __shared__ float Ws[128 * 17];
  __shared__ float xs[16][17];
  int tid = threadIdx.x;
#pragma unroll
  for (int it = 0; it < 8; ++it) {
    int idx = it * 256 + tid;
    int j = idx >> 4, k = idx & 15;
    Ws[j * 17 + k] = Wp[idx];
  }
  int n0 = blockIdx.x * 16;
  { int nn = tid >> 4, k = tid & 15;
    xs[nn][k] = x[(size_t)(n0 + nn) * 16 + k]; }
  __syncthreads();
  int j = tid & 127, g = tid >> 7;
  float acc[8];
#pragma unroll
  for (int r = 0; r < 8; ++r) acc[r] = 0.f;
#pragma unroll
  for (int k = 0; k < 16; ++k) {
    float w = Ws[j * 17 + k];
#pragma unroll
    for (int r = 0; r < 8; ++r) acc[r] += xs[g * 8 + r][k] * w;
  }
#pragma unroll
  for (int r = 0; r < 8; ++r)
    feat[(size_t)(n0 + g * 8 + r) * 128 + j] = f2b(acc[r]);
}

// ---------- vectors: a<6: vecs[a][k] = sum_j Wg[j,k]*(al|ar)[j];  a==6: c[j] = sum_k W2[j,k]*bias[k]
__global__ __launch_bounds__(128) void vec_k(const float* Wg0, const float* al0, const float* ar0,
                                             const float* Wg1, const float* al1, const float* ar1,
                                             const float* Wg2, const float* al2, const float* ar2,
                                             const float* Wl, const float* bias,
                                             float* __restrict__ vecs) {
  int a = blockIdx.x;
  int j = threadIdx.x;
  float s = 0.f;
  if (a < 6) {
    const float* W = (a < 2) ? Wg0 : (a < 4) ? Wg1 : Wg2;
    const float* v = (a == 0) ? al0 : (a == 1) ? ar0 : (a == 2) ? al1 : (a == 3) ? ar1 : (a == 4) ? al2 : ar2;
    for (int i = 0; i < 128; ++i) s += W[i * 128 + j] * v[i];
  } else {
    for (int i = 0; i < 128; ++i) s += Wl[(size_t)j * 256 + 128 + i] * bias[i];
  }
  vecs[a * 128 + j] = s;
}

// ---------- per-node logits, single pass per ntype
// y=0 (net): a=1 er0, a=2 el1, a=4 el2, a=5 er2;  y=1 (cell): a=0 el0, a=3 er1
__global__ __launch_bounds__(256) void logits_k(const u16* __restrict__ feat_net, const u16* __restrict__ feat_cell,
                                                const float* __restrict__ vecs, float* __restrict__ outs) {
  __shared__ float vs[6 * 128];
  int tid = threadIdx.x;
#pragma unroll
  for (int it = 0; it < 3; ++it) vs[it * 256 + tid] = vecs[it * 256 + tid];
  __syncthreads();
  int y = blockIdx.y;
  const u16* f = y ? feat_cell : feat_net;
  int n = blockIdx.x * 256 + tid;
  if (n >= NN) return;
  const u16* row = f + (size_t)n * 128;
  if (y == 0) {
    float s1 = 0.f, s2 = 0.f, s4 = 0.f, s5 = 0.f;
#pragma unroll
    for (int k = 0; k < 128; k += 8) {
      short8 u = *(const short8*)(row + k);
#pragma unroll
      for (int t = 0; t < 8; ++t) {
        float fv = b2f((u16)u[t]);
        s1 += fv * vs[1 * 128 + k + t]; s2 += fv * vs[2 * 128 + k + t];
        s4 += fv * vs[4 * 128 + k + t]; s5 += fv * vs[5 * 128 + k + t];
      }
    }
    outs[(size_t)1 * NN + n] = s1; outs[(size_t)2 * NN + n] = s2;
    outs[(size_t)4 * NN + n] = s4; outs[(size_t)5 * NN + n] = s5;
  } else {
    float s0 = 0.f, s3 = 0.f;
#pragma unroll
    for (int k = 0; k < 128; k += 8) {
      short8 u = *(const short8*)(row + k);
#pragma unroll
      for (int t = 0; t < 8; ++t) {
        float fv = b2f((u16)u[t]);
        s0 += fv * vs[0 * 128 + k + t]; s3 += fv * vs[3 * 128 + k + t];
      }
    }
    outs[(size_t)0 * NN + n] = s0; outs[(size_t)3 * NN + n] = s3;
  }
}

// ---------- histogram over (bucket, sub) keys
__global__ __launch_bounds__(256) void bhist_k(const int* __restrict__ dst0, const int* __restrict__ dst1,
                                               const int* __restrict__ dst2, int* __restrict__ bcnt) {
  int r = blockIdx.y;
  const int* dst = (r == 0) ? dst0 : (r == 1) ? dst1 : dst2;
  int e = blockIdx.x * 256 + threadIdx.x;
  if (e >= NE) return;
  int key = ((dst[e] >> 7) << 4) | (e & (NSUB - 1));
  atomicAdd(&bcnt[r * NK + key], 1);
}

// ---------- exclusive scan of NK counters per relation (one 1024-block each)
__global__ __launch_bounds__(1024) void bscan_k(const int* __restrict__ bcnt, int* __restrict__ bptr,
                                                int* __restrict__ bcur) {
  int r = blockIdx.x, t = threadIdx.x;
  const int* c = bcnt + (size_t)r * NK;
  int* p = bptr + (size_t)r * (NK + 1);
  int* cur = bcur + (size_t)r * NK;
  const int CH = 13;  // 13*1024 = 13312 >= NK
  int base = t * CH;
  int loc[CH]; int s = 0;
#pragma unroll
  for (int i = 0; i < CH; ++i) {
    int idx = base + i;
    int v = (idx < NK) ? c[idx] : 0;
    loc[i] = s; s += v;
  }
  __shared__ int ss[1024];
  ss[t] = s; __syncthreads();
  for (int off = 1; off < 1024; off <<= 1) {
    int u = (t >= off) ? ss[t - off] : 0;
    __syncthreads();
    ss[t] += u;
    __syncthreads();
  }
  int ex = ss[t] - s;
#pragma unroll
  for (int i = 0; i < CH; ++i) {
    int idx = base + i;
    if (idx < NK) { int e = ex + loc[i]; p[idx] = e; cur[idx] = e; }
  }
  if (t == 1023) p[NK] = ss[1023];
}

// ---------- scatter rec = (local_dst<<17)|src into (bucket,sub) segment
__global__ __launch_bounds__(256) void bscatter_k(const int* __restrict__ src0, const int* __restrict__ dst0,
                                                  const int* __restrict__ src1, const int* __restrict__ dst1,
                                                  const int* __restrict__ src2, const int* __restrict__ dst2,
                                                  int* __restrict__ bcur, u32* __restrict__ recs) {
  int r = blockIdx.y;
  const int* src = (r == 0) ? src0 : (r == 1) ? src1 : src2;
  const int* dst = (r == 0) ? dst0 : (r == 1) ? dst1 : dst2;
  int e = blockIdx.x * 256 + threadIdx.x;
  if (e >= NE) return;
  int sN = src[e], dN = dst[e];
  int key = ((dN >> 7) << 4) | (e & (NSUB - 1));
  int pos = atomicAdd(&bcur[(size_t)r * NK + key], 1);
  recs[(size_t)r * NE + pos] = ((u32)(dN & 127) << 17) | (u32)sN;
}

// ---------- per-bucket LDS counting sort (in place) + node rowptr
__global__ __launch_bounds__(256) void sort_k(u32* __restrict__ recs, const int* __restrict__ bptr,
                                              int* __restrict__ rowptr) {
  int r = blockIdx.y, b = blockIdx.x, tid = threadIdx.x;
  const int* p = bptr + (size_t)r * (NK + 1);
  u32* rec = recs + (size_t)r * NE;
  int* rp = rowptr + (size_t)r * (NN + 1);
  int base = p[b * NSUB], end = p[b * NSUB + NSUB];
  int cnt = end - base; if (cnt > BCAP) cnt = BCAP;   // statistically impossible to exceed
  __shared__ u32 rs[BCAP];
  __shared__ int hist[128], excl[128], cur[128];
  for (int i = tid; i < cnt; i += 256) rs[i] = rec[base + i];
  if (tid < 128) hist[tid] = 0;
  __syncthreads();
  for (int i = tid; i < cnt; i += 256) atomicAdd(&hist[rs[i] >> 17], 1);
  __syncthreads();
  if (tid < 128) cur[tid] = hist[tid];
  __syncthreads();
  for (int off = 1; off < 128; off <<= 1) {
    int v = 0;
    if (tid < 128 && tid >= off) v = cur[tid - off];
    __syncthreads();
    if (tid < 128) cur[tid] += v;
    __syncthreads();
  }
  if (tid < 128) {
    int e = cur[tid] - hist[tid];      // exclusive
    excl[tid] = e;
    int node = b * 128 + tid;
    if (node < NN) rp[node] = base + e;
  }
  if (b == NB - 1 && tid == 0) rp[NN] = p[NK];
  if (tid < 128) cur[tid] = excl[tid];
  __syncthreads();
  for (int i = tid; i < cnt; i += 256) {
    u32 v = rs[i];
    int pos = atomicAdd(&cur[v >> 17], 1);
    rec[base + pos] = v & 0x1FFFFu;    // store src only, node-sorted
  }
}

// ---------- aggregation: one wave per dst node, register accumulation
// out[n] (+)= (sum_e x_e h[src_e]) / (sum_e x_e);  x = exp(leaky(el[src]+er[n]))
template<int RMW>
__global__ __launch_bounds__(256) void agg_k(const u16* __restrict__ h, const u32* __restrict__ srecs,
                                             const int* __restrict__ rp,
                                             const float* __restrict__ el, const float* __restrict__ er,
                                             float* __restrict__ out) {
  int n = blockIdx.x * 4 + (threadIdx.x >> 6);
  if (n >= NN) return;
  int lane = threadIdx.x & 63;
  int start = rp[n], end = rp[n + 1];
  float2* o = (float2*)(out + (size_t)n * 128) + lane;
  if (start == end) { if (!RMW) *o = make_float2(0.f, 0.f); return; }
  float ern = er[n];
  float2 acc = make_float2(0.f, 0.f);
  float s = 0.f;
  for (int e = start; e < end; ++e) {
    int src = (int)srecs[e];
    float l = el[src] + ern;
    l = (l >= 0.f) ? l : 0.2f * l;
    float x = __expf(l);
    s += x;
    u32 hv = *(const u32*)(h + (size_t)src * 128 + 2 * lane);
    acc.x += x * b2f((u16)(hv & 0xffff));
    acc.y += x * b2f((u16)(hv >> 16));
  }
  float inv = 1.f / s;
  float2 prev = RMW ? *o : make_float2(0.f, 0.f);
  prev.x += acc.x * inv; prev.y += acc.y * inv;
  *o = prev;
}

// ---------- bf16 GEMM (up to 3 jobs): C[n][j] = sum_k A[n][k] * W[j*ldw+woff+k], bf16 out
struct BJob { const u16* A; const float* W; int ldw; int woff; u16* C; };
struct BJobs3 { BJob j[3]; };
__global__ __launch_bounds__(256) void gemm_bf_k(BJobs3 jobs) {
  BJob jb = jobs.j[blockIdx.y];
  __shared__ u16 Alds[64 * SP];
  __shared__ u16 Wlds[128 * SP];
  const int tid = threadIdx.x;
  const int row0 = blockIdx.x * 64;
#pragma unroll
  for (int it = 0; it < 16; ++it) {
    int idx = it * 256 + tid;
    int r = idx >> 5, c = (idx & 31) << 2;
    float4 v = *(const float4*)(jb.W + (size_t)r * jb.ldw + jb.woff + c);
    ushort4 p; p.x = f2b(v.x); p.y = f2b(v.y); p.z = f2b(v.z); p.w = f2b(v.w);
    *(ushort4*)(&Wlds[r * SP + c]) = p;
  }
#pragma unroll
  for (int it = 0; it < 4; ++it) {
    int idx = it * 256 + tid;
    int r = idx >> 4, c = (idx & 15) << 3;
    int gr = row0 + r;
    short8 v = short8{0, 0, 0, 0, 0, 0, 0, 0};
    if (gr < NN) v = *(const short8*)(jb.A + (size_t)gr * 128 + c);
    *(short8*)(&Alds[r * SP + c]) = v;
  }
  __syncthreads();
  const int lane = tid & 63, wv = tid >> 6;
  const int m16 = lane & 15, quad = lane >> 4;
  floatx4 acc[8];
#pragma unroll
  for (int c = 0; c < 8; ++c) acc[c] = floatx4{0.f, 0.f, 0.f, 0.f};
  const u16* arow = &Alds[(wv * 16 + m16) * SP + quad * 8];
  const u16* brow = &Wlds[m16 * SP + quad * 8];
#pragma unroll
  for (int kk = 0; kk < 4; ++kk) {
    bf16x8 a = *(const bf16x8*)(arow + kk * 32);
#pragma unroll
    for (int c = 0; c < 8; ++c) {
      bf16x8 bfr = *(const bf16x8*)(brow + c * 16 * SP + kk * 32);
      acc[c] = __builtin_amdgcn_mfma_f32_16x16x32_bf16(a, bfr, acc[c], 0, 0, 0);
    }
  }
#pragma unroll
  for (int c = 0; c < 8; ++c) {
    int col = c * 16 + m16;
#pragma unroll
    for (int r = 0; r < 4; ++r) {
      int grow = row0 + wv * 16 + quad * 4 + r;
      if (grow < NN) jb.C[(size_t)grow * 128 + col] = f2b(acc[c][r]);
    }
  }
}

// ---------- fused concat-linear-relu (up to 2 jobs): C = relu(P + (A+bias) @ W2.T), fp32 out
struct FJob { const float* A; const u16* P; float* C; };
struct FJobs2 { FJob j[2]; const float* W; const float* bias; };
__global__ __launch_bounds__(256) void fused_k(FJobs2 jobs) {
  FJob jb = jobs.j[blockIdx.y];
  __shared__ u16 Alds[64 * SP];
  __shared__ u16 Wlds[128 * SP];
  const int tid = threadIdx.x;
  const int row0 = blockIdx.x * 64;
#pragma unroll
  for (int it = 0; it < 16; ++it) {
    int idx = it * 256 + tid;
    int r = idx >> 5, c = (idx & 31) << 2;
    float4 v = *(const float4*)(jobs.W + (size_t)r * 256 + 128 + c);
    ushort4 p; p.x = f2b(v.x); p.y = f2b(v.y); p.z = f2b(v.z); p.w = f2b(v.w);
    *(ushort4*)(&Wlds[r * SP + c]) = p;
  }
#pragma unroll
  for (int it = 0; it < 8; ++it) {
    int idx = it * 256 + tid;
    int r = idx >> 5, col = (idx & 31) << 2;
    int gr = row0 + r;
    float4 v = make_float4(0.f, 0.f, 0.f, 0.f);
    if (gr < NN) v = *(const float4*)(jb.A + (size_t)gr * 128 + col);
    v.x += jobs.bias[col]; v.y += jobs.bias[col + 1];
    v.z += jobs.bias[col + 2]; v.w += jobs.bias[col + 3];
    ushort4 p; p.x = f2b(v.x); p.y = f2b(v.y); p.z = f2b(v.z); p.w = f2b(v.w);
    *(ushort4*)(&Alds[r * SP + col]) = p;
  }
  __syncthreads();
  const int lane = tid & 63, wv = tid >> 6;
  const int m16 = lane & 15, quad = lane >> 4;
  floatx4 acc[8];
#pragma unroll
  for (int c = 0; c < 8; ++c) acc[c] = floatx4{0.f, 0.f, 0.f, 0.f};
  const u16* arow = &Alds[(wv * 16 + m16) * SP + quad * 8];
  const u16* brow = &Wlds[m16 * SP + quad * 8];
#pragma unroll
  for (int kk = 0; kk < 4; ++kk) {
    bf16x8 a = *(const bf16x8*)(arow + kk * 32);
#pragma unroll
    for (int c = 0; c < 8; ++c) {
      bf16x8 bfr = *(const bf16x8*)(brow + c * 16 * SP + kk * 32);
      acc[c] = __builtin_amdgcn_mfma_f32_16x16x32_bf16(a, bfr, acc[c], 0, 0, 0);
    }
  }
#pragma unroll
  for (int c = 0; c < 8; ++c) {
    int col = c * 16 + m16;
#pragma unroll
    for (int r = 0; r < 4; ++r) {
      int grow = row0 + wv * 16 + quad * 4 + r;
      if (grow < NN) {
        float v = acc[c][r] + b2f(jb.P[(size_t)grow * 128 + col]);
        jb.C[(size_t)grow * 128 + col] = fmaxf(v, 0.f);
      }
    }
  }
}

// ---------- r0 cell shortcut: buf_cell = relu(P_cell + W2@bias)   (agg input was all zeros)
__global__ __launch_bounds__(256) void elem_k(const u16* __restrict__ P, const float* __restrict__ vecs,
                                              float* __restrict__ out) {
  __shared__ float cs[128];
  if (threadIdx.x < 128) cs[threadIdx.x] = vecs[6 * 128 + threadIdx.x];
  __syncthreads();
  size_t idx = ((size_t)blockIdx.x * 256 + threadIdx.x) * 8;
  if (idx >= (size_t)NN * 128) return;
  int col = (int)(idx & 127);
  short8 u = *(const short8*)(P + idx);
  float4 o0, o1;
  o0.x = fmaxf(b2f((u16)u[0]) + cs[col + 0], 0.f);
  o0.y = fmaxf(b2f((u16)u[1]) + cs[col + 1], 0.f);
  o0.z = fmaxf(b2f((u16)u[2]) + cs[col + 2], 0.f);
  o0.w = fmaxf(b2f((u16)u[3]) + cs[col + 3], 0.f);
  o1.x = fmaxf(b2f((u16)u[4]) + cs[col + 4], 0.f);
  o1.y = fmaxf(b2f((u16)u[5]) + cs[col + 5], 0.f);
  o1.z = fmaxf(b2f((u16)u[6]) + cs[col + 6], 0.f);
  o1.w = fmaxf(b2f((u16)u[7]) + cs[col + 7], 0.f);
  *(float4*)(out + idx) = o0;
  *(float4*)(out + idx + 4) = o1;
}

extern "C" void kernel_launch(void* const* d_in, const int* in_sizes, int n_in,
                              void* d_out, int out_size, void* d_ws, size_t ws_size,
                              hipStream_t stream) {
  const float* x_net   = (const float*)d_in[0];
  const float* x_cell  = (const float*)d_in[1];
  const float* Wp_net  = (const float*)d_in[2];
  const float* Wp_cell = (const float*)d_in[3];
  const float* Wg[3] = {(const float*)d_in[4], (const float*)d_in[7], (const float*)d_in[10]};
  const float* al[3] = {(const float*)d_in[5], (const float*)d_in[8], (const float*)d_in[11]};
  const float* ar[3] = {(const float*)d_in[6], (const float*)d_in[9], (const float*)d_in[12]};
  const float* Wl    = (const float*)d_in[13];
  const float* bias  = (const float*)d_in[14];
  const int* src[3] = {(const int*)d_in[15], (const int*)d_in[17], (const int*)d_in[19]};
  const int* dst[3] = {(const int*)d_in[16], (const int*)d_in[18], (const int*)d_in[20]};

  char* ws = (char*)d_ws;
  size_t off = 0;
  auto alloc = [&](size_t b) { void* p = ws + off; off = (off + b + 255) & ~(size_t)255; return p; };
  u16*  feat_net  = (u16*)alloc((size_t)NN * 128 * 2);
  u16*  feat_cell = (u16*)alloc((size_t)NN * 128 * 2);
  u16*  hbuf      = (u16*)alloc((size_t)NN * 128 * 2);
  u16*  P_net     = (u16*)alloc((size_t)NN * 128 * 2);
  u16*  P_cell    = (u16*)alloc((size_t)NN * 128 * 2);
  float* buf_net  = (float*)alloc((size_t)NN * 128 * 4);
  float* buf_cell = (float*)alloc((size_t)NN * 128 * 4);
  float* vecs     = (float*)alloc(7 * 128 * 4);
  float* logit    = (float*)alloc((size_t)6 * NN * 4);
  int*   bcnt     = (int*)alloc((size_t)3 * NK * 4);
  int*   bcur     = (int*)alloc((size_t)3 * NK * 4);
  int*   bptr     = (int*)alloc((size_t)3 * (NK + 1) * 4);
  int*   rowptr   = (int*)alloc((size_t)3 * (NN + 1) * 4);
  u32*   recs     = (u32*)alloc((size_t)3 * NE * 4);
  // ~245 MB total

  hipMemsetAsync(bcnt, 0, (size_t)3 * NK * 4, stream);

  proj_k<<<dim3(NN / 16, 2), 256, 0, stream>>>(x_net, x_cell, Wp_net, Wp_cell, feat_net, feat_cell);
  vec_k<<<7, 128, 0, stream>>>(Wg[0], al[0], ar[0], Wg[1], al[1], ar[1], Wg[2], al[2], ar[2], Wl, bias, vecs);
  logits_k<<<dim3((NN + 255) / 256, 2), 256, 0, stream>>>(feat_net, feat_cell, vecs, logit);

  bhist_k<<<dim3((NE + 255) / 256, 3), 256, 0, stream>>>(dst[0], dst[1], dst[2], bcnt);
  bscan_k<<<3, 1024, 0, stream>>>(bcnt, bptr, bcur);
  bscatter_k<<<dim3((NE + 255) / 256, 3), 256, 0, stream>>>(src[0], dst[0], src[1], dst[1], src[2], dst[2],
                                                            bcur, recs);
  sort_k<<<dim3(NB, 3), 256, 0, stream>>>(recs, bptr, rowptr);

  const int gb = (NN + 63) / 64;  // 1563
  {
    BJobs3 jobs;
    jobs.j[0] = {feat_net,  Wl,    256, 0, P_net};
    jobs.j[1] = {feat_cell, Wl,    256, 0, P_cell};
    jobs.j[2] = {feat_cell, Wg[0], 128, 0, hbuf};   // h0 = feat_cell @ Wg0.T
    gemm_bf_k<<<dim3(gb, 3), 256, 0, stream>>>(jobs);
  }

  float* out_f = (float*)d_out;  // [2,N,D] fp32: net then cell
  const int ab = (NN + 3) / 4;   // 25000

  // ---- r = 0 : cell -> net
  agg_k<0><<<ab, 256, 0, stream>>>(hbuf, recs, rowptr, logit, logit + (size_t)NN, buf_net);
  {
    FJobs2 jobs; jobs.W = Wl; jobs.bias = bias;
    jobs.j[0] = {buf_net, P_net, buf_net}; jobs.j[1] = jobs.j[0];
    fused_k<<<dim3(gb, 1), 256, 0, stream>>>(jobs);
  }
  elem_k<<<(NN * 128 / 8 + 255) / 256, 256, 0, stream>>>(P_cell, vecs, buf_cell);

  // ---- r = 1 : net -> cell
  {
    BJobs3 jobs;
    jobs.j[0] = {feat_net, Wg[1], 128, 0, hbuf};
    jobs.j[1] = jobs.j[0]; jobs.j[2] = jobs.j[0];
    gemm_bf_k<<<dim3(gb, 1), 256, 0, stream>>>(jobs);
  }
  agg_k<1><<<ab, 256, 0, stream>>>(hbuf, recs + (size_t)NE, rowptr + (NN + 1),
                                   logit + (size_t)2 * NN, logit + (size_t)3 * NN, buf_cell);
  {
    FJobs2 jobs; jobs.W = Wl; jobs.bias = bias;
    jobs.j[0] = {buf_net, P_net, buf_net};
    jobs.j[1] = {buf_cell, P_cell, buf_cell};
    fused_k<<<dim3(gb, 2), 256, 0, stream>>>(jobs);
  }

  // ---- r = 2 : net -> net
  {
    BJobs3 jobs;
    jobs.j[0] = {feat_net, Wg[2], 128, 0, hbuf};
    jobs.j[1] = jobs.j[0]; jobs.j[2] = jobs.j[0];
    gemm_bf_k<<<dim3(gb, 1), 256, 0, stream>>>(jobs);
  }
  agg_k<1><<<ab, 256, 0, stream>>>(hbuf, recs + (size_t)2 * NE, rowptr + 2 * (NN + 1),
                                   logit + (size_t)4 * NN, logit + (size_t)5 * NN, buf_net);
  {
    FJobs2 jobs; jobs.W = Wl; jobs.bias = bias;
    jobs.j[0] = {buf_net, P_net, out_f};
    jobs.j[1] = {buf_cell, P_cell, out_f + (size_t)NN * 128};
    fused_k<<<dim3(gb, 2), 256, 0, stream>>>(jobs);
  }
}